// Round 1
// baseline (613.209 us; speedup 1.0000x reference)
//
#include <hip/hip_runtime.h>

#define NN 100000
#define HH 512
#define GG 512
#define NPACK 1280

typedef unsigned short u16;
typedef __bf16 bf16x8 __attribute__((ext_vector_type(8)));
typedef float f32x4 __attribute__((ext_vector_type(4)));
typedef __attribute__((address_space(1))) void gvoid_t;
typedef __attribute__((address_space(3))) void lvoid_t;

__device__ __forceinline__ u16 f2bf(float f) {
    unsigned u = __float_as_uint(f);
    unsigned r = u + 0x7FFFu + ((u >> 16) & 1u);   // RNE
    return (u16)(r >> 16);
}
__device__ __forceinline__ float bf2f(u16 b) {
    return __uint_as_float(((unsigned)b) << 16);
}

// ---------------- prep: packed W^T (bf16), packed bias, packed wvec ----------------
// packed col n: [0,256) = ga_g_w1 col n ; [256,768) = ga_n_w col n-256 ; [768,1280) = g_w1 col n-768
__global__ void k_prep(const float* __restrict__ gw1, const float* __restrict__ gb1,
                       const float* __restrict__ gw2v,
                       const float* __restrict__ nw, const float* __restrict__ nb,
                       const float* __restrict__ aw1, const float* __restrict__ ab1,
                       const float* __restrict__ aw2,
                       u16* __restrict__ WT, float* __restrict__ bias, float* __restrict__ wvec) {
    int idx = blockIdx.x * blockDim.x + threadIdx.x;
    int stride = gridDim.x * blockDim.x;
    for (int i = idx; i < NPACK * 512; i += stride) {
        int n = i >> 9, k = i & 511;
        float v;
        if (n < 256)      v = gw1[k * 256 + n];
        else if (n < 768) v = nw[k * 512 + (n - 256)];
        else              v = aw1[k * 512 + (n - 768)];
        WT[n * 512 + k] = f2bf(v);   // W^T: row n contiguous in k
    }
    for (int n = idx; n < NPACK; n += stride) {
        float bi, wv;
        if (n < 256)      { bi = gb1[n];       wv = gw2v[n]; }
        else if (n < 768) { bi = nb[n - 256];  wv = 0.f; }
        else {
            bi = ab1[n - 768];
            float s = 0.f;
            for (int h = 0; h < 8; ++h) s += aw2[(n - 768) * 8 + h];
            wv = s * 0.125f;   // wbar = mean over heads
        }
        bias[n] = bi; wvec[n] = wv;
    }
}

// ---------------- init: scores to biases, zero graph_embedding ----------------
__global__ void k_init(const float* __restrict__ gb2, const float* __restrict__ ab2,
                       float* __restrict__ gs, float* __restrict__ as_, float* __restrict__ out_emb) {
    float b2 = gb2[0];
    float bb = 0.f;
    for (int h = 0; h < 8; ++h) bb += ab2[h];
    bb *= 0.125f;
    int stride = gridDim.x * blockDim.x;
    for (int i = blockIdx.x * blockDim.x + threadIdx.x; i < GG * HH; i += stride) {
        out_emb[i] = 0.f;
        if (i < NN) { gs[i] = b2; as_[i] = bb; }
    }
    // NN < GG*HH (100000 < 262144), so the guard above covers all scores
}

// ---------------- convert x fp32 -> bf16 ----------------
__global__ void k_convert_x(const float* __restrict__ x, u16* __restrict__ xb) {
    int stride = gridDim.x * blockDim.x;
    const int tot = NN * HH / 4;
    for (int i = blockIdx.x * blockDim.x + threadIdx.x; i < tot; i += stride) {
        float4 v = reinterpret_cast<const float4*>(x)[i];
        ushort4 o;
        o.x = f2bf(v.x); o.y = f2bf(v.y); o.z = f2bf(v.z); o.w = f2bf(v.w);
        reinterpret_cast<ushort4*>(xb)[i] = o;
    }
}

// ---------------- segment bounds (batch is sorted) ----------------
__global__ void k_bounds(const int* __restrict__ batch, int* __restrict__ starts) {
    int g = blockIdx.x * blockDim.x + threadIdx.x;
    if (g > GG) return;
    if (g == GG) { starts[GG] = NN; return; }
    int lo = 0, hi = NN;
    while (lo < hi) { int mid = (lo + hi) >> 1; if (batch[mid] < g) lo = mid + 1; else hi = mid; }
    starts[g] = lo;
}

// ---------------- fused MFMA GEMM: C = relu(x @ Wpacked + bias), fused epilogues ----------------
// grid: (10 n-tiles, 782 m-tiles), 256 threads (4 waves in 2x2)
// nt 0-1: gate score partial (dot with wvec, atomicAdd)  | nt 2-5: store xt bf16 | nt 6-9: att score partial
__global__ __launch_bounds__(256, 2)
void k_gemm(const u16* __restrict__ A, const u16* __restrict__ B,
            const float* __restrict__ bias, const float* __restrict__ wvec,
            u16* __restrict__ xt, float* __restrict__ gs, float* __restrict__ as_) {
    __shared__ __align__(16) char lds[16384];
    char* ldsA = lds;
    char* ldsB = lds + 8192;

    const int tid = threadIdx.x;
    const int lane = tid & 63;
    const int w = tid >> 6;
    const int wr = w >> 1, wc = w & 1;
    const int nt = blockIdx.x;
    const int m0 = blockIdx.y * 128;
    const int n0 = nt * 128;

    f32x4 acc[4][4];
#pragma unroll
    for (int i = 0; i < 4; ++i)
#pragma unroll
        for (int j = 0; j < 4; ++j) acc[i][j] = {0.f, 0.f, 0.f, 0.f};

    // staging: chunk c (0..511) holds row (c>>6)*16 + (c&15), k-bytes [((c>>4)&3)*16 .. +15]
    const int rb = tid >> 6, kq = (tid >> 4) & 3, r16 = tid & 15;
    int rowA0 = m0 + rb * 16 + r16;        if (rowA0 >= NN) rowA0 = NN - 1;
    int rowA1 = m0 + (rb + 4) * 16 + r16;  if (rowA1 >= NN) rowA1 = NN - 1;
    const u16* gA0 = A + (size_t)rowA0 * 512 + kq * 8;
    const u16* gA1 = A + (size_t)rowA1 * 512 + kq * 8;
    const u16* gB0 = B + (size_t)(n0 + rb * 16 + r16) * 512 + kq * 8;
    const u16* gB1 = B + (size_t)(n0 + (rb + 4) * 16 + r16) * 512 + kq * 8;
    char* lA0 = ldsA + tid * 16;
    char* lA1 = ldsA + tid * 16 + 4096;
    char* lB0 = ldsB + tid * 16;
    char* lB1 = ldsB + tid * 16 + 4096;

    for (int kt = 0; kt < 16; ++kt) {
        __builtin_amdgcn_global_load_lds((gvoid_t*)gA0, (lvoid_t*)lA0, 16, 0, 0);
        __builtin_amdgcn_global_load_lds((gvoid_t*)gA1, (lvoid_t*)lA1, 16, 0, 0);
        __builtin_amdgcn_global_load_lds((gvoid_t*)gB0, (lvoid_t*)lB0, 16, 0, 0);
        __builtin_amdgcn_global_load_lds((gvoid_t*)gB1, (lvoid_t*)lB1, 16, 0, 0);
        __syncthreads();   // compiler emits vmcnt(0) drain here

        bf16x8 a[4], b[4];
#pragma unroll
        for (int i = 0; i < 4; ++i)
            a[i] = *(const bf16x8*)(ldsA + (wr * 4 + i) * 1024 + lane * 16);
#pragma unroll
        for (int j = 0; j < 4; ++j)
            b[j] = *(const bf16x8*)(ldsB + (wc * 4 + j) * 1024 + lane * 16);
#pragma unroll
        for (int i = 0; i < 4; ++i)
#pragma unroll
            for (int j = 0; j < 4; ++j)
                acc[i][j] = __builtin_amdgcn_mfma_f32_16x16x32_bf16(a[i], b[j], acc[i][j], 0, 0, 0);
        __syncthreads();
        gA0 += 32; gA1 += 32; gB0 += 32; gB1 += 32;
    }

    // epilogue. C/D layout: col = lane&15, row = (lane>>4)*4 + reg   [m89-verified]
    const int quad = lane >> 4;
    const int l16 = lane & 15;
    if (nt >= 2 && nt < 6) {
        // xt region: relu(acc + bias) -> bf16 store
#pragma unroll
        for (int i = 0; i < 4; ++i) {
#pragma unroll
            for (int r = 0; r < 4; ++r) {
                int rg = m0 + wr * 64 + i * 16 + quad * 4 + r;
                if (rg < NN) {
#pragma unroll
                    for (int j = 0; j < 4; ++j) {
                        int colg = n0 + wc * 64 + j * 16 + l16;
                        float v = acc[i][j][r] + bias[colg];
                        v = v > 0.f ? v : 0.f;
                        xt[(size_t)rg * 512 + (colg - 256)] = f2bf(v);
                    }
                }
            }
        }
    } else {
        float* target = (nt < 2) ? gs : as_;
#pragma unroll
        for (int i = 0; i < 4; ++i) {
#pragma unroll
            for (int r = 0; r < 4; ++r) {
                float p = 0.f;
#pragma unroll
                for (int j = 0; j < 4; ++j) {
                    int colg = n0 + wc * 64 + j * 16 + l16;
                    float v = acc[i][j][r] + bias[colg];
                    v = v > 0.f ? v : 0.f;
                    p += v * wvec[colg];
                }
                p += __shfl_xor(p, 1); p += __shfl_xor(p, 2);
                p += __shfl_xor(p, 4); p += __shfl_xor(p, 8);
                int rg = m0 + wr * 64 + i * 16 + quad * 4 + r;
                if (l16 == 0 && rg < NN) atomicAdd(target + rg, p);
            }
        }
    }
}

// ---------------- per-graph segment max + exp-sum (both scores) ----------------
__global__ void k_seg(const float* __restrict__ gs, const float* __restrict__ as_,
                      const int* __restrict__ starts,
                      float* __restrict__ mg, float* __restrict__ dg,
                      float* __restrict__ ma, float* __restrict__ da) {
    int g = blockIdx.x;
    int s0 = starts[g], s1 = starts[g + 1];
    int tid = threadIdx.x, lane = tid & 63, w = tid >> 6;
    __shared__ float red[8];
    float lmg = -3.0e38f, lma = -3.0e38f;
    for (int i = s0 + tid; i < s1; i += 256) {
        lmg = fmaxf(lmg, gs[i]); lma = fmaxf(lma, as_[i]);
    }
    for (int o = 32; o; o >>= 1) {
        lmg = fmaxf(lmg, __shfl_xor(lmg, o));
        lma = fmaxf(lma, __shfl_xor(lma, o));
    }
    if (lane == 0) { red[w] = lmg; red[4 + w] = lma; }
    __syncthreads();
    float Mg = fmaxf(fmaxf(red[0], red[1]), fmaxf(red[2], red[3]));
    float Ma = fmaxf(fmaxf(red[4], red[5]), fmaxf(red[6], red[7]));
    __syncthreads();
    float sg = 0.f, sa = 0.f;
    for (int i = s0 + tid; i < s1; i += 256) {
        sg += expf(gs[i] - Mg); sa += expf(as_[i] - Ma);
    }
    for (int o = 32; o; o >>= 1) { sg += __shfl_xor(sg, o); sa += __shfl_xor(sa, o); }
    if (lane == 0) { red[w] = sg; red[4 + w] = sa; }
    __syncthreads();
    if (tid == 0) {
        mg[g] = Mg; ma[g] = Ma;
        dg[g] = red[0] + red[1] + red[2] + red[3];
        da[g] = red[4] + red[5] + red[6] + red[7];
    }
}

// ---------------- normalize: gate weights + attention output ----------------
__global__ void k_final(const float* __restrict__ gs, const float* __restrict__ as_,
                        const int* __restrict__ batch,
                        const float* __restrict__ mg, const float* __restrict__ dg,
                        const float* __restrict__ ma, const float* __restrict__ da,
                        float* __restrict__ gate, float* __restrict__ attn) {
    int stride = gridDim.x * blockDim.x;
    for (int i = blockIdx.x * blockDim.x + threadIdx.x; i < NN; i += stride) {
        int b = batch[i];
        gate[i] = expf(gs[i] - mg[b]) / (dg[b] + 1e-16f);
        attn[i] = expf(as_[i] - ma[b]) / (da[b] + 1e-16f);
    }
}

// ---------------- graph embedding: segment-weighted sum of xt ----------------
// grid (4 node-parts, 512 graphs); each thread owns 2 adjacent cols (ushort2 load)
__global__ void k_emb(const u16* __restrict__ xt, const float* __restrict__ gate,
                      const int* __restrict__ starts, float* __restrict__ out) {
    int g = blockIdx.y;
    int part = blockIdx.x;
    int s0 = starts[g], s1 = starts[g + 1];
    int len = s1 - s0;
    int p0 = s0 + (len * part) / 4, p1 = s0 + (len * (part + 1)) / 4;
    int c2 = threadIdx.x;   // 0..255 -> cols 2*c2, 2*c2+1
    float a0 = 0.f, a1 = 0.f;
    for (int n = p0; n < p1; ++n) {
        float gn = gate[n];
        ushort2 u = reinterpret_cast<const ushort2*>(xt + (size_t)n * 512)[c2];
        a0 += gn * bf2f(u.x);
        a1 += gn * bf2f(u.y);
    }
    atomicAdd(&out[g * 512 + 2 * c2], a0);
    atomicAdd(&out[g * 512 + 2 * c2 + 1], a1);
}

extern "C" void kernel_launch(void* const* d_in, const int* in_sizes, int n_in,
                              void* d_out, int out_size, void* d_ws, size_t ws_size,
                              hipStream_t stream) {
    const float* x       = (const float*)d_in[0];
    const int*   batch   = (const int*)d_in[1];
    const float* ga_g_w1 = (const float*)d_in[2];
    const float* ga_g_b1 = (const float*)d_in[3];
    const float* ga_g_w2 = (const float*)d_in[4];
    const float* ga_g_b2 = (const float*)d_in[5];
    const float* ga_n_w  = (const float*)d_in[6];
    const float* ga_n_b  = (const float*)d_in[7];
    const float* g_w1    = (const float*)d_in[8];
    const float* g_b1    = (const float*)d_in[9];
    const float* g_w2    = (const float*)d_in[10];
    const float* g_b2    = (const float*)d_in[11];

    float* out_emb = (float*)d_out;                  // (512, 512)
    float* out_att = out_emb + GG * HH;              // (100000,)

    // workspace carve-up (all 256B aligned)
    char* p = (char*)d_ws;
    size_t off = 0;
    auto alloc = [&](size_t bytes) -> char* {
        char* q = p + off;
        off += (bytes + 255) & ~(size_t)255;
        return q;
    };
    u16*   xb    = (u16*)  alloc((size_t)NN * HH * 2);      // x in bf16
    u16*   xt    = (u16*)  alloc((size_t)NN * HH * 2);      // relu(x@ga_n_w+b) in bf16
    u16*   WT    = (u16*)  alloc((size_t)NPACK * 512 * 2);  // packed W^T bf16
    float* bias  = (float*)alloc(NPACK * 4);
    float* wvec  = (float*)alloc(NPACK * 4);
    float* gs    = (float*)alloc((size_t)NN * 4);           // gate scores
    float* as_   = (float*)alloc((size_t)NN * 4);           // att scores
    float* gate  = (float*)alloc((size_t)NN * 4);           // normalized gate
    float* mg    = (float*)alloc(GG * 4);
    float* dg    = (float*)alloc(GG * 4);
    float* ma    = (float*)alloc(GG * 4);
    float* da    = (float*)alloc(GG * 4);
    int*   starts= (int*)  alloc((GG + 1) * 4);

    k_prep<<<2560, 256, 0, stream>>>(ga_g_w1, ga_g_b1, ga_g_w2, ga_n_w, ga_n_b,
                                     g_w1, g_b1, g_w2, WT, bias, wvec);
    k_init<<<1024, 256, 0, stream>>>(ga_g_b2, g_b2, gs, as_, out_emb);
    k_convert_x<<<8192, 256, 0, stream>>>(x, xb);
    k_bounds<<<3, 256, 0, stream>>>(batch, starts);
    k_gemm<<<dim3(10, 782), 256, 0, stream>>>(xb, WT, bias, wvec, xt, gs, as_);
    k_seg<<<GG, 256, 0, stream>>>(gs, as_, starts, mg, dg, ma, da);
    k_final<<<400, 256, 0, stream>>>(gs, as_, batch, mg, dg, ma, da, gate, out_att);
    k_emb<<<dim3(4, GG), 256, 0, stream>>>(xt, gate, starts, out_emb);
}

// Round 2
// 601.822 us; speedup vs baseline: 1.0189x; 1.0189x over previous
//
#include <hip/hip_runtime.h>

#define NN 100000
#define HH 512
#define GG 512
#define NPACK 1280

typedef unsigned short u16;
typedef __bf16 bf16x8 __attribute__((ext_vector_type(8)));
typedef unsigned short u16x8 __attribute__((ext_vector_type(8)));
typedef float f32x4 __attribute__((ext_vector_type(4)));
typedef __attribute__((address_space(1))) void gvoid_t;
typedef __attribute__((address_space(3))) void lvoid_t;

__device__ __forceinline__ u16 f2bf(float f) {
    unsigned u = __float_as_uint(f);
    unsigned r = u + 0x7FFFu + ((u >> 16) & 1u);   // RNE
    return (u16)(r >> 16);
}
__device__ __forceinline__ float bf2f(u16 b) {
    return __uint_as_float(((unsigned)b) << 16);
}

// ---------------- prep: packed W^T bf16 + bias + wvec + zero out_emb + segment bounds ----
// packed col n: [0,256) = ga_g_w1 col n ; [256,768) = ga_n_w col n-256 ; [768,1280) = g_w1 col n-768
__global__ void k_prep(const float* __restrict__ gw1, const float* __restrict__ gb1,
                       const float* __restrict__ gw2v,
                       const float* __restrict__ nw, const float* __restrict__ nb,
                       const float* __restrict__ aw1, const float* __restrict__ ab1,
                       const float* __restrict__ aw2, const int* __restrict__ batch,
                       u16* __restrict__ WT, float* __restrict__ bias, float* __restrict__ wvec,
                       float* __restrict__ out_emb, int* __restrict__ starts) {
    int idx = blockIdx.x * blockDim.x + threadIdx.x;
    int stride = gridDim.x * blockDim.x;
    for (int i = idx; i < NPACK * 512; i += stride) {
        int n = i >> 9, k = i & 511;
        float v;
        if (n < 256)      v = gw1[k * 256 + n];
        else if (n < 768) v = nw[k * 512 + (n - 256)];
        else              v = aw1[k * 512 + (n - 768)];
        WT[n * 512 + k] = f2bf(v);   // row n contiguous in k
    }
    for (int n = idx; n < NPACK; n += stride) {
        float bi, wv;
        if (n < 256)      { bi = gb1[n];       wv = gw2v[n]; }
        else if (n < 768) { bi = nb[n - 256];  wv = 0.f; }
        else {
            bi = ab1[n - 768];
            float s = 0.f;
            for (int h = 0; h < 8; ++h) s += aw2[(n - 768) * 8 + h];
            wv = s * 0.125f;
        }
        bias[n] = bi; wvec[n] = wv;
    }
    for (int i = idx; i < GG * HH; i += stride) out_emb[i] = 0.f;
    for (int g = idx; g <= GG; g += stride) {
        if (g == GG) { starts[GG] = NN; continue; }
        int lo = 0, hi = NN;
        while (lo < hi) { int mid = (lo + hi) >> 1; if (batch[mid] < g) lo = mid + 1; else hi = mid; }
        starts[g] = lo;
    }
}

// ---------------- fused GEMM: A (128 rows) in registers, stream B through 8KB LDS ------
// block = 128 m-rows x all 1280 packed cols (20 strips of 64). 4 waves stacked on m.
// nt 0-3: gate score | nt 4-11: xt store | nt 12-19: att score. Scores in regs, no atomics.
__global__ __launch_bounds__(256, 2)
void k_gemm(const float* __restrict__ X, const u16* __restrict__ B,
            const float* __restrict__ bias, const float* __restrict__ wvec,
            const float* __restrict__ gb2, const float* __restrict__ ab2,
            u16* __restrict__ xt, float* __restrict__ gs, float* __restrict__ as_) {
    __shared__ __align__(16) char ldsB[8192];

    const int tid = threadIdx.x;
    const int lane = tid & 63;
    const int w = tid >> 6;                 // wave -> rows [w*32, w*32+32)
    const int m0 = blockIdx.x * 128;
    const int r16 = lane & 15, kq = lane >> 4;

    float b2 = gb2[0];
    float bb = 0.f;
#pragma unroll
    for (int h = 0; h < 8; ++h) bb += ab2[h];
    bb *= 0.125f;

    // ---- A panel: global fp32 -> convert -> registers (read once, per-lane frags) ----
    bf16x8 a_reg[2][16];                    // 2 m-subs x 16 k-steps = 128 VGPRs
#pragma unroll
    for (int i = 0; i < 2; ++i) {
        int row = m0 + w * 32 + i * 16 + r16;
        if (row >= NN) row = NN - 1;
        const float* xp = X + (size_t)row * 512 + kq * 8;
#pragma unroll
        for (int kt = 0; kt < 16; ++kt) {
            float4 f0 = *(const float4*)(xp + kt * 32);
            float4 f1 = *(const float4*)(xp + kt * 32 + 4);
            u16x8 u;
            u[0] = f2bf(f0.x); u[1] = f2bf(f0.y); u[2] = f2bf(f0.z); u[3] = f2bf(f0.w);
            u[4] = f2bf(f1.x); u[5] = f2bf(f1.y); u[6] = f2bf(f1.z); u[7] = f2bf(f1.w);
            a_reg[i][kt] = __builtin_bit_cast(bf16x8, u);
        }
    }

    // B staging thread constants: chunk tid -> (nsub, kq2, r16b), two issues (kk=0/1)
    const int nsub = (tid >> 6) & 3, kq2 = (tid >> 4) & 3, r16b = tid & 15;
    const u16* gB0 = B + (size_t)(nsub * 16 + r16b) * 512 + kq2 * 8;
    char* lB0 = ldsB + tid * 16;
    char* lB1 = ldsB + 4096 + tid * 16;

    float sg[2][4], sa[2][4];
#pragma unroll
    for (int i = 0; i < 2; ++i)
#pragma unroll
        for (int r = 0; r < 4; ++r) { sg[i][r] = 0.f; sa[i][r] = 0.f; }

    const int quad = lane >> 4, l16 = lane & 15;

    for (int nt = 0; nt < 20; ++nt) {
        f32x4 acc[2][4];
#pragma unroll
        for (int i = 0; i < 2; ++i)
#pragma unroll
            for (int j = 0; j < 4; ++j) acc[i][j] = {0.f, 0.f, 0.f, 0.f};

        const u16* gBn = gB0 + (size_t)nt * 64 * 512;
#pragma unroll
        for (int kt2 = 0; kt2 < 8; ++kt2) {
            __builtin_amdgcn_global_load_lds((gvoid_t*)(gBn + kt2 * 64),      (lvoid_t*)lB0, 16, 0, 0);
            __builtin_amdgcn_global_load_lds((gvoid_t*)(gBn + kt2 * 64 + 32), (lvoid_t*)lB1, 16, 0, 0);
            __syncthreads();
#pragma unroll
            for (int kk = 0; kk < 2; ++kk) {
                bf16x8 b[4];
#pragma unroll
                for (int j = 0; j < 4; ++j)
                    b[j] = *(const bf16x8*)(ldsB + kk * 4096 + j * 1024 + lane * 16);
#pragma unroll
                for (int i = 0; i < 2; ++i)
#pragma unroll
                    for (int j = 0; j < 4; ++j)
                        acc[i][j] = __builtin_amdgcn_mfma_f32_16x16x32_bf16(
                            a_reg[i][kt2 * 2 + kk], b[j], acc[i][j], 0, 0, 0);
            }
            __syncthreads();
        }

        // ---- per-strip epilogue. C/D: col = lane&15, row = quad*4 + reg [m89] ----
        const int n0 = nt * 64;
        if (nt >= 4 && nt < 12) {
#pragma unroll
            for (int i = 0; i < 2; ++i) {
#pragma unroll
                for (int r = 0; r < 4; ++r) {
                    int rg = m0 + w * 32 + i * 16 + quad * 4 + r;
                    if (rg < NN) {
#pragma unroll
                        for (int j = 0; j < 4; ++j) {
                            int colg = n0 + j * 16 + l16;
                            float v = acc[i][j][r] + bias[colg];
                            v = fmaxf(v, 0.f);
                            xt[(size_t)rg * 512 + (colg - 256)] = f2bf(v);
                        }
                    }
                }
            }
        } else if (nt < 4) {
#pragma unroll
            for (int i = 0; i < 2; ++i)
#pragma unroll
                for (int r = 0; r < 4; ++r) {
                    float p = 0.f;
#pragma unroll
                    for (int j = 0; j < 4; ++j) {
                        int colg = n0 + j * 16 + l16;
                        float v = acc[i][j][r] + bias[colg];
                        v = fmaxf(v, 0.f);
                        p += v * wvec[colg];
                    }
                    sg[i][r] += p;
                }
        } else {
#pragma unroll
            for (int i = 0; i < 2; ++i)
#pragma unroll
                for (int r = 0; r < 4; ++r) {
                    float p = 0.f;
#pragma unroll
                    for (int j = 0; j < 4; ++j) {
                        int colg = n0 + j * 16 + l16;
                        float v = acc[i][j][r] + bias[colg];
                        v = fmaxf(v, 0.f);
                        p += v * wvec[colg];
                    }
                    sa[i][r] += p;
                }
        }
    }

    // ---- final scores: reduce over the 16 col-lanes, one coalesced write, no atomics ----
#pragma unroll
    for (int i = 0; i < 2; ++i)
#pragma unroll
        for (int r = 0; r < 4; ++r) {
            float pg = sg[i][r], pa = sa[i][r];
            pg += __shfl_xor(pg, 1); pg += __shfl_xor(pg, 2);
            pg += __shfl_xor(pg, 4); pg += __shfl_xor(pg, 8);
            pa += __shfl_xor(pa, 1); pa += __shfl_xor(pa, 2);
            pa += __shfl_xor(pa, 4); pa += __shfl_xor(pa, 8);
            int rg = m0 + w * 32 + i * 16 + quad * 4 + r;
            if (l16 == 0 && rg < NN) {
                gs[rg] = pg + b2;
                as_[rg] = pa + bb;
            }
        }
}

// ---------------- per-graph segment max + exp-sum (both scores) ----------------
__global__ void k_seg(const float* __restrict__ gs, const float* __restrict__ as_,
                      const int* __restrict__ starts,
                      float* __restrict__ mg, float* __restrict__ dg,
                      float* __restrict__ ma, float* __restrict__ da) {
    int g = blockIdx.x;
    int s0 = starts[g], s1 = starts[g + 1];
    int tid = threadIdx.x, lane = tid & 63, w = tid >> 6;
    __shared__ float red[8];
    float lmg = -3.0e38f, lma = -3.0e38f;
    for (int i = s0 + tid; i < s1; i += 256) {
        lmg = fmaxf(lmg, gs[i]); lma = fmaxf(lma, as_[i]);
    }
    for (int o = 32; o; o >>= 1) {
        lmg = fmaxf(lmg, __shfl_xor(lmg, o));
        lma = fmaxf(lma, __shfl_xor(lma, o));
    }
    if (lane == 0) { red[w] = lmg; red[4 + w] = lma; }
    __syncthreads();
    float Mg = fmaxf(fmaxf(red[0], red[1]), fmaxf(red[2], red[3]));
    float Ma = fmaxf(fmaxf(red[4], red[5]), fmaxf(red[6], red[7]));
    __syncthreads();
    float sgv = 0.f, sav = 0.f;
    for (int i = s0 + tid; i < s1; i += 256) {
        sgv += expf(gs[i] - Mg); sav += expf(as_[i] - Ma);
    }
    for (int o = 32; o; o >>= 1) { sgv += __shfl_xor(sgv, o); sav += __shfl_xor(sav, o); }
    if (lane == 0) { red[w] = sgv; red[4 + w] = sav; }
    __syncthreads();
    if (tid == 0) {
        mg[g] = Mg; ma[g] = Ma;
        dg[g] = red[0] + red[1] + red[2] + red[3];
        da[g] = red[4] + red[5] + red[6] + red[7];
    }
}

// ---------------- normalize: gate weights + attention output ----------------
__global__ void k_final(const float* __restrict__ gs, const float* __restrict__ as_,
                        const int* __restrict__ batch,
                        const float* __restrict__ mg, const float* __restrict__ dg,
                        const float* __restrict__ ma, const float* __restrict__ da,
                        float* __restrict__ gate, float* __restrict__ attn) {
    int stride = gridDim.x * blockDim.x;
    for (int i = blockIdx.x * blockDim.x + threadIdx.x; i < NN; i += stride) {
        int b = batch[i];
        gate[i] = expf(gs[i] - mg[b]) / (dg[b] + 1e-16f);
        attn[i] = expf(as_[i] - ma[b]) / (da[b] + 1e-16f);
    }
}

// ---------------- graph embedding: segment-weighted sum of xt ----------------
__global__ void k_emb(const u16* __restrict__ xt, const float* __restrict__ gate,
                      const int* __restrict__ starts, float* __restrict__ out) {
    int g = blockIdx.y;
    int part = blockIdx.x;
    int s0 = starts[g], s1 = starts[g + 1];
    int len = s1 - s0;
    int p0 = s0 + (len * part) / 4, p1 = s0 + (len * (part + 1)) / 4;
    int c2 = threadIdx.x;
    float a0 = 0.f, a1 = 0.f;
    for (int n = p0; n < p1; ++n) {
        float gn = gate[n];
        ushort2 u = reinterpret_cast<const ushort2*>(xt + (size_t)n * 512)[c2];
        a0 += gn * bf2f(u.x);
        a1 += gn * bf2f(u.y);
    }
    atomicAdd(&out[g * 512 + 2 * c2], a0);
    atomicAdd(&out[g * 512 + 2 * c2 + 1], a1);
}

extern "C" void kernel_launch(void* const* d_in, const int* in_sizes, int n_in,
                              void* d_out, int out_size, void* d_ws, size_t ws_size,
                              hipStream_t stream) {
    const float* x       = (const float*)d_in[0];
    const int*   batch   = (const int*)d_in[1];
    const float* ga_g_w1 = (const float*)d_in[2];
    const float* ga_g_b1 = (const float*)d_in[3];
    const float* ga_g_w2 = (const float*)d_in[4];
    const float* ga_g_b2 = (const float*)d_in[5];
    const float* ga_n_w  = (const float*)d_in[6];
    const float* ga_n_b  = (const float*)d_in[7];
    const float* g_w1    = (const float*)d_in[8];
    const float* g_b1    = (const float*)d_in[9];
    const float* g_w2    = (const float*)d_in[10];
    const float* g_b2    = (const float*)d_in[11];

    float* out_emb = (float*)d_out;                  // (512, 512)
    float* out_att = out_emb + GG * HH;              // (100000,)

    char* p = (char*)d_ws;
    size_t off = 0;
    auto alloc = [&](size_t bytes) -> char* {
        char* q = p + off;
        off += (bytes + 255) & ~(size_t)255;
        return q;
    };
    u16*   xt    = (u16*)  alloc((size_t)NN * HH * 2);      // relu(x@ga_n_w+b) bf16
    u16*   WT    = (u16*)  alloc((size_t)NPACK * 512 * 2);  // packed W^T bf16
    float* bias  = (float*)alloc(NPACK * 4);
    float* wvec  = (float*)alloc(NPACK * 4);
    float* gs    = (float*)alloc((size_t)NN * 4);
    float* as_   = (float*)alloc((size_t)NN * 4);
    float* gate  = (float*)alloc((size_t)NN * 4);
    float* mg    = (float*)alloc(GG * 4);
    float* dg    = (float*)alloc(GG * 4);
    float* ma    = (float*)alloc(GG * 4);
    float* da    = (float*)alloc(GG * 4);
    int*   starts= (int*)  alloc((GG + 1) * 4);

    k_prep<<<2560, 256, 0, stream>>>(ga_g_w1, ga_g_b1, ga_g_w2, ga_n_w, ga_n_b,
                                     g_w1, g_b1, g_w2, batch, WT, bias, wvec, out_emb, starts);
    k_gemm<<<782, 256, 0, stream>>>(x, WT, bias, wvec, ga_g_b2, g_b2, xt, gs, as_);
    k_seg<<<GG, 256, 0, stream>>>(gs, as_, starts, mg, dg, ma, da);
    k_final<<<400, 256, 0, stream>>>(gs, as_, batch, mg, dg, ma, da, gate, out_att);
    k_emb<<<dim3(4, GG), 256, 0, stream>>>(xt, gate, starts, out_emb);
}